// Round 12
// baseline (1020.950 us; speedup 1.0000x reference)
//
#include <hip/hip_runtime.h>

// ---------------------------------------------------------------------------
// SGCN: 2-layer GraphSAGE('gcn') + EdgeWeightNorm('right') + mean-pool + FC
// N=100k nodes, E=3.2M edges, G=64 graphs, F=64 feats, fp32 throughout.
//
// R11 -> R12: agg VALUBusy only 27% -> fuse FC (readlane x VGPR-resident W
// column) and the graph pool into agg's epilogue; waves take CONTIGUOUS node
// chunks so layer-2 pooling is run-length with ~2 atomic flushes/wave.
//  * fc + fcpool kernels deleted from main path; t2 never materialized;
//    t1 roundtrip removed (~100MB streaming + 2 launches saved).
//  * gather inner loop untouched (R7/R8/R10/R11 all pin at 3.2TB/s).
// Pipeline: memset, binfill2, csrsort, aggfc(L1), aggfc(L2+pool), out.
// ---------------------------------------------------------------------------

#define CH2  4096   // edges per binfill2 block
#define BK   1024   // max buckets
#define NB   128    // nodes per bucket
#define CAPB 5120   // bucket capacity (mean 4096 + 16 sigma)
#define SRCMASK ((1 << 18) - 1)

__device__ __forceinline__ float readlane_f(float v, int l) {
    return __int_as_float(__builtin_amdgcn_readlane(__float_as_int(v), l));
}

// scan-free binfill: LDS hist -> pair-scan -> global span reserve ->
// LDS scatter (dl packed in .x) -> contiguous flush into bucket regions.
__global__ __launch_bounds__(512) void k_binfill2(
        const int* __restrict__ esrc, const int* __restrict__ edst,
        const float* __restrict__ ew, int* __restrict__ cursor,
        int2* __restrict__ bsw, int E, int B) {
    __shared__ int2 stg[CH2];            // 32 KB
    __shared__ int h[BK];                //  4 KB
    __shared__ int lcur[BK];             //  4 KB
    __shared__ int gb[BK];               //  4 KB
    __shared__ int sc[512];              //  2 KB
    const int tid = threadIdx.x;

    for (int i = tid; i < BK; i += 512) h[i] = 0;
    __syncthreads();
    int e0 = blockIdx.x * CH2;
    int e1 = min(E, e0 + CH2);
    for (int e = e0 + tid; e < e1; e += 512)
        atomicAdd(&h[edst[e] >> 7], 1);
    __syncthreads();
    // pair scan: thread t owns entries 2t, 2t+1
    int a0 = h[2 * tid], a1 = h[2 * tid + 1];
    int s  = a0 + a1;
    sc[tid] = s;
    __syncthreads();
    for (int off = 1; off < 512; off <<= 1) {
        int t = (tid >= off) ? sc[tid - off] : 0;
        __syncthreads();
        sc[tid] += t;
        __syncthreads();
    }
    int base = sc[tid] - s;               // exclusive over pairs
    lcur[2 * tid]     = base;
    lcur[2 * tid + 1] = base + a0;
    gb[2 * tid]     = a0 ? atomicAdd(&cursor[2 * tid],     a0) : 0;
    gb[2 * tid + 1] = a1 ? atomicAdd(&cursor[2 * tid + 1], a1) : 0;
    __syncthreads();
    // scatter into bucket-grouped staging; dl packed into .x bits 18..24
    for (int e = e0 + tid; e < e1; e += 512) {
        int d = edst[e];
        int b = d >> 7;
        int p = atomicAdd(&lcur[b], 1);
        stg[p] = make_int2(((d & 127) << 18) | esrc[e], __float_as_int(ew[e]));
    }
    __syncthreads();
    // contiguous flush: wave w handles buckets w, w+8, ...
    const int wid = tid >> 6, lane = tid & 63;
    for (int b = wid; b < B; b += 8) {
        int len = h[b];
        if (!len) continue;
        int lb = lcur[b] - len;
        int g  = gb[b];
        int wlen = min(len, CAPB - g);
        if (wlen <= 0) continue;
        size_t gbase = (size_t)b * CAPB + g;
        for (int i = lane; i < wlen; i += 64)
            bsw[gbase + i] = stg[lb + i];
    }
}

// counting-sort a bucket's edges in LDS; flush node-major (dl stripped).
__global__ __launch_bounds__(512) void k_csrsort(
        const int2* __restrict__ bsw, const int* __restrict__ cursor,
        int2* __restrict__ csr, int* __restrict__ off, int* __restrict__ fill,
        int N) {
    __shared__ int2 se[CAPB];            // 40 KB
    __shared__ int cur[NB];
    __shared__ int pfx[NB];
    const int b = blockIdx.x, tid = threadIdx.x;
    if (tid < NB) cur[tid] = 0;
    __syncthreads();
    const int cnt = min(cursor[b], CAPB);
    const int2* __restrict__ eb = bsw + (size_t)b * CAPB;
    for (int i = tid; i < cnt; i += 512)
        atomicAdd(&cur[eb[i].x >> 18], 1);   // pass1: counts
    __syncthreads();
    if (tid < NB) pfx[tid] = cur[tid];
    __syncthreads();
    for (int o = 1; o < NB; o <<= 1) {       // Hillis-Steele over 128
        int t = 0;
        if (tid < NB && tid >= o) t = pfx[tid - o];
        __syncthreads();
        if (tid < NB) pfx[tid] += t;
        __syncthreads();
    }
    if (tid < NB) {
        int excl = pfx[tid] - cur[tid];
        int node = b * NB + tid;
        if (node < N) { off[node] = b * CAPB + excl; fill[node] = cur[tid]; }
        cur[tid] = excl;                     // reuse as scatter cursor
    }
    __syncthreads();
    for (int i = tid; i < cnt; i += 512) {
        int2 e = eb[i];
        int p = atomicAdd(&cur[e.x >> 18], 1);
        se[p] = e;                           // pass2: LDS scatter
    }
    __syncthreads();
    int2* __restrict__ cb = csr + (size_t)b * CAPB;
    for (int i = tid; i < cnt; i += 512) {
        int2 e = se[i];
        cb[i] = make_int2(e.x & SRCMASK, e.y);   // contiguous full-line flush
    }
}

// ---------------------------------------------------------------------------
// fused agg + FC (+ optional graph pool). Wave = contiguous node chunk.
// gather: lane = (slot[2], f8[32]), float2 slices (R8 body).
// epilogue: per-lane W column in 64 VGPRs, 64x readlane+fma, relu;
//   do_pool=0 -> store rows to outbuf; do_pool=1 -> run-length pool to hg.
// ---------------------------------------------------------------------------
__global__ __launch_bounds__(256, 4) void k_aggfc(
        const float* __restrict__ x, const int* __restrict__ off,
        const int* __restrict__ cnt_arr, const int2* __restrict__ csr,
        const float* __restrict__ W, const float* __restrict__ bvec,
        float* __restrict__ outbuf, const int* __restrict__ gid,
        float* __restrict__ hg, float* __restrict__ cntg,
        int N, int do_pool) {
    const int lane   = threadIdx.x & 63;
    const int slot   = lane >> 5;
    const int f8     = lane & 31;
    const int wave   = (blockIdx.x * blockDim.x + threadIdx.x) >> 6;
    const int nwaves = (gridDim.x * blockDim.x) >> 6;
    const float2* __restrict__ xv = (const float2*)x;

    float wc[64];
    #pragma unroll
    for (int f = 0; f < 64; ++f) wc[f] = W[f * 64 + lane];   // coalesced rows
    const float bias = bvec[lane];

    const int per   = (N + nwaves - 1) / nwaves;
    const int start = wave * per;
    const int end   = min(N, start + per);
    if (start >= N) return;

    int   curg = -1;
    float accp = 0.0f;
    int   cp   = 0;

    int cnt_p   = cnt_arr[start];
    int start_p = off[start];
    for (int node = start; node < end; ++node) {
        const int cnt = cnt_p, st = start_p;
        if (node + 1 < end) {               // contiguous header prefetch
            cnt_p   = cnt_arr[node + 1];
            start_p = off[node + 1];
        }
        int2 ee = make_int2(0, 0);          // zero-pad: w=0, s=0
        if (lane < cnt) ee = csr[st + lane];
        float2 acc0 = {0.f, 0.f}, acc1 = {0.f, 0.f};
        float  sw = 0.0f;
        for (int bk = 0; bk < cnt; bk += 64) {
            int   s_l = ee.x;
            float w_l = __int_as_float(ee.y);
            int2 en = make_int2(0, 0);
            int  rem = cnt - bk - 64;
            if (lane < rem) en = csr[st + bk + 64 + lane];
            sw += w_l;
            #pragma unroll
            for (int half = 0; half < 2; ++half) {   // 32 edges per stage
                float  w[16];
                float2 v[16];
                #pragma unroll
                for (int k = 0; k < 16; ++k) {       // issue 16 gathers
                    int idx = half * 32 + 2 * k + slot;
                    int s   = __shfl(s_l, idx);
                    w[k]    = __shfl(w_l, idx);
                    v[k]    = xv[(size_t)s * 32 + f8];
                }
                #pragma unroll
                for (int k = 0; k < 16; k += 2) {    // consume
                    acc0.x = fmaf(w[k],   v[k].x,   acc0.x);
                    acc0.y = fmaf(w[k],   v[k].y,   acc0.y);
                    acc1.x = fmaf(w[k+1], v[k+1].x, acc1.x);
                    acc1.y = fmaf(w[k+1], v[k+1].y, acc1.y);
                }
            }
            ee = en;
        }
        acc0.x += acc1.x; acc0.y += acc1.y;
        acc0.x += __shfl_xor(acc0.x, 32);   // both halves now hold slot-sum
        acc0.y += __shfl_xor(acc0.y, 32);
        #pragma unroll
        for (int mask = 1; mask <= 32; mask <<= 1) sw += __shfl_xor(sw, mask);
        float invw = (sw > 0.0f) ? (1.0f / sw) : 0.0f;
        float invd = 1.0f / ((float)cnt + 1.0f);
        float2 xs = xv[(size_t)node * 32 + f8];      // all lanes (dup ok)
        float2 hn;
        hn.x = (acc0.x * invw + xs.x) * invd;        // feature 2*f8
        hn.y = (acc0.y * invw + xs.y) * invd;        // feature 2*f8+1
        // FC: o[lane] = bias + sum_f hn_f * W[f][lane]; feature f lives at
        // lane (f>>1), component (f&1)
        float o0 = bias, o1 = 0.f;
        #pragma unroll
        for (int j = 0; j < 32; ++j) {
            float hx = readlane_f(hn.x, j);
            float hy = readlane_f(hn.y, j);
            o0 = fmaf(hx, wc[2 * j],     o0);
            o1 = fmaf(hy, wc[2 * j + 1], o1);
        }
        float o = fmaxf(o0 + o1, 0.0f);
        if (!do_pool) {
            outbuf[(size_t)node * 64 + lane] = o;    // coalesced 256B
        } else {
            int g = gid[node];                       // wave-uniform
            if (g != curg) {
                if (cp > 0) {
                    atomicAdd(&hg[curg * 64 + lane], accp);
                    if (lane == 0) atomicAdd(&cntg[curg], (float)cp);
                }
                curg = g; accp = 0.0f; cp = 0;
            }
            accp += o;
            ++cp;
        }
    }
    if (do_pool && cp > 0) {
        atomicAdd(&hg[curg * 64 + lane], accp);
        if (lane == 0) atomicAdd(&cntg[curg], (float)cp);
    }
}

__global__ void k_out(const float* __restrict__ hg, const float* __restrict__ cntg,
                      const float* __restrict__ Wc, const float* __restrict__ bc,
                      float* __restrict__ out, int G) {
    int t = blockIdx.x * blockDim.x + threadIdx.x;
    if (t >= G * 2) return;
    int g = t >> 1, c = t & 1;
    float ct = fmaxf(cntg[g], 1.0f);
    float o  = bc[c];
    for (int f = 0; f < 64; ++f)
        o += (hg[g * 64 + f] / ct) * Wc[f * 2 + c];
    out[t] = o;
}

// ---- fallback kernels ----
__global__ void k_fill_pad(const int* __restrict__ esrc, const int* __restrict__ edst,
                           const float* __restrict__ ew, int* __restrict__ fill,
                           int2* __restrict__ csr, int E, int CAP) {
    int e = blockIdx.x * blockDim.x + threadIdx.x;
    if (e < E) {
        int d = edst[e];
        int p = atomicAdd(&fill[d], 1);
        if (p < CAP)
            csr[(size_t)d * CAP + p] = make_int2(esrc[e], __float_as_int(ew[e]));
    }
}

__global__ void k_cnt(const int* __restrict__ edst, int* __restrict__ cnt, int E) {
    int e = blockIdx.x * blockDim.x + threadIdx.x;
    if (e < E) atomicAdd(&cnt[edst[e]], 1);
}

__global__ void k_off(const int* __restrict__ cnt, int* __restrict__ off,
                      int* __restrict__ fill, int* __restrict__ cursor, int N) {
    int i    = blockIdx.x * blockDim.x + threadIdx.x;
    int lane = threadIdx.x & 63;
    int c    = (i < N) ? cnt[i] : 0;
    int pref = c;
    #pragma unroll
    for (int d = 1; d < 64; d <<= 1) {
        int t = __shfl_up(pref, d);
        if (lane >= d) pref += t;
    }
    int total = __shfl(pref, 63);
    int base  = 0;
    if (lane == 63) base = atomicAdd(cursor, total);
    base = __shfl(base, 63);
    if (i < N) {
        int p = base + pref - c;
        off[i]  = p;
        fill[i] = p;
    }
}

__global__ void k_fill(const int* __restrict__ esrc, const int* __restrict__ edst,
                       const float* __restrict__ ew, int* __restrict__ fill,
                       int2* __restrict__ csr, int E) {
    int e = blockIdx.x * blockDim.x + threadIdx.x;
    if (e < E) {
        int d = edst[e];
        int p = atomicAdd(&fill[d], 1);
        csr[p] = make_int2(esrc[e], __float_as_int(ew[e]));
    }
}

extern "C" void kernel_launch(void* const* d_in, const int* in_sizes, int n_in,
                              void* d_out, int out_size, void* d_ws, size_t ws_size,
                              hipStream_t stream) {
    const float* in_feat = (const float*)d_in[0];
    const float* ew      = (const float*)d_in[1];
    const float* W1      = (const float*)d_in[2];
    const float* b1      = (const float*)d_in[3];
    const float* W2      = (const float*)d_in[4];
    const float* b2      = (const float*)d_in[5];
    const float* Wc      = (const float*)d_in[6];
    const float* bc      = (const float*)d_in[7];
    const int*   esrc    = (const int*)d_in[8];
    const int*   edst    = (const int*)d_in[9];
    const int*   gid     = (const int*)d_in[10];

    const int E = in_sizes[1];
    const int N = in_sizes[10];
    const int G = out_size / 2;
    float* outp = (float*)d_out;

    auto alignup = [](size_t x) { return (x + 15) & ~(size_t)15; };
    char* base = (char*)d_ws;
    const int AGG_BLK = 2048;

    // ---- main path: bucketed sort chain + fused agg (R12) ----
    const int B     = (N + NB - 1) / NB;               // 128-node buckets
    const int NBLK2 = (E + CH2 - 1) / CH2;

    size_t zhdr  = ((size_t)G * 64 + G + BK) * 4;      // hg, cntg, cursor
    size_t o_off = alignup(zhdr);
    size_t o_fil = o_off + alignup((size_t)N * 4);
    size_t o_bsw = o_fil + alignup((size_t)N * 4);
    size_t o_csr = o_bsw + alignup((size_t)B * CAPB * 8);
    size_t o_t1  = o_csr + alignup((size_t)B * CAPB * 8);
    size_t needB = o_t1 + (size_t)N * 64 * 4;

    bool cap_ok = ((size_t)E / B) + 512 < CAPB && N <= (1 << 18);

    if (ws_size >= needB && B <= BK && cap_ok) {
        float* hg     = (float*)base;
        float* cntg   = hg + (size_t)G * 64;
        int*   cursor = (int*)(cntg + G);
        int*   off    = (int*)(base + o_off);
        int*   fill   = (int*)(base + o_fil);
        int2*  bsw    = (int2*)(base + o_bsw);
        int2*  csr    = (int2*)(base + o_csr);
        float* t1     = (float*)(base + o_t1);

        hipMemsetAsync(d_ws, 0, zhdr, stream);   // hg, cntg, cursor
        k_binfill2<<<NBLK2, 512, 0, stream>>>(esrc, edst, ew, cursor, bsw, E, B);
        k_csrsort <<<B, 512, 0, stream>>>(bsw, cursor, csr, off, fill, N);
        k_aggfc<<<AGG_BLK, 256, 0, stream>>>(in_feat, off, fill, csr, W1, b1,
                                             t1, nullptr, nullptr, nullptr, N, 0);
        k_aggfc<<<AGG_BLK, 256, 0, stream>>>(t1, off, fill, csr, W2, b2,
                                             nullptr, gid, hg, cntg, N, 1);
        k_out  <<<1, 128, 0, stream>>>(hg, cntg, Wc, bc, outp, G);
        return;
    }

    // ---- fallback 1: one-pass padded scatter + fused agg ----
    const int CAP = 96;
    size_t hdr    = ((size_t)G * 64 + G + 1 + N) * 4;
    size_t needB2 = alignup(hdr) + alignup((size_t)N * CAP * 8)
                  + alignup((size_t)N * 64 * 4);
    if (ws_size >= needB2) {
        size_t o = 0;
        float* hg     = (float*)(base + o);
        float* cntg   = hg + (size_t)G * 64;
        int*   fill   = (int*)(cntg + G) + 1;
        o += alignup(hdr);
        int2*  csr = (int2*)(base + o);  o += alignup((size_t)N * CAP * 8);
        float* t1  = (float*)(base + o);

        hipMemsetAsync(d_ws, 0, hdr, stream);
        k_fill_pad<<<(E + 255) / 256, 256, 0, stream>>>(esrc, edst, ew, fill, csr, E, CAP);
        // padded CSR: off[node] = node*CAP encoded via off=nullptr path not
        // available here, so build off implicitly: reuse k_aggfc with off
        // array == precomputed? Simplest: treat CAP layout via off/fill:
        // off[node] = node*CAP. Use k_off-style init kernel-free: fill
        // already holds counts; create off with a tiny kernel-free trick is
        // not possible -> use compact fallback below instead if this matters.
        // Here: use fill as cnt and synthesize off on the fly is unsupported;
        // fall through to compact path for safety.
    }

    // ---- fallback 2: 3-pass compact CSR + fused agg ----
    {
        size_t o = 0;
        float* hg     = (float*)(base + o);
        float* cntg   = hg + (size_t)G * 64;
        int*   cursor = (int*)(cntg + G);
        int*   cnt    = cursor + 1;
        o += alignup(hdr);
        int*   off  = (int*)(base + o);  o += alignup((size_t)N * 4);
        int*   fill = (int*)(base + o);  o += alignup((size_t)N * 4);
        int2*  csr  = (int2*)(base + o); o += alignup((size_t)E * 8);
        float* t1   = (float*)(base + o);

        hipMemsetAsync(d_ws, 0, hdr, stream);
        k_cnt <<<(E + 255) / 256, 256, 0, stream>>>(edst, cnt, E);
        k_off <<<(N + 255) / 256, 256, 0, stream>>>(cnt, off, fill, cursor, N);
        k_fill<<<(E + 255) / 256, 256, 0, stream>>>(esrc, edst, ew, fill, csr, E);
        k_aggfc<<<AGG_BLK, 256, 0, stream>>>(in_feat, off, cnt, csr, W1, b1,
                                             t1, nullptr, nullptr, nullptr, N, 0);
        k_aggfc<<<AGG_BLK, 256, 0, stream>>>(t1, off, cnt, csr, W2, b2,
                                             nullptr, gid, hg, cntg, N, 1);
        k_out  <<<1, 128, 0, stream>>>(hg, cntg, Wc, bc, outp, G);
    }
}

// Round 13
// 938.645 us; speedup vs baseline: 1.0877x; 1.0877x over previous
//
#include <hip/hip_runtime.h>

// ---------------------------------------------------------------------------
// SGCN: 2-layer GraphSAGE('gcn') + EdgeWeightNorm('right') + mean-pool + FC
// N=100k nodes, E=3.2M edges, G=64 graphs, F=64 feats, fp32 throughout.
//
// R12 -> R13: R12's fused aggfc SPILLED wc[64] (VGPR=64 reported, FETCH
// 368MB->1.32GB = per-node scratch re-reads of the spilled W column).
// Fix: gather staging 16 -> 4 (R8 showed depth beyond ~4 is collapsed by
// the compiler anyway; gather pins at 3.2TB/s). wc[64] + staging 12 + misc
// fits under the 128-VGPR cap -> no spill. Rest of R12 unchanged.
// Pipeline: memset, binfill2, csrsort, aggfc(L1), aggfc(L2+pool), out.
// ---------------------------------------------------------------------------

#define CH2  4096   // edges per binfill2 block
#define BK   1024   // max buckets
#define NB   128    // nodes per bucket
#define CAPB 5120   // bucket capacity (mean 4096 + 16 sigma)
#define SRCMASK ((1 << 18) - 1)

__device__ __forceinline__ float readlane_f(float v, int l) {
    return __int_as_float(__builtin_amdgcn_readlane(__float_as_int(v), l));
}

// scan-free binfill: LDS hist -> pair-scan -> global span reserve ->
// LDS scatter (dl packed in .x) -> contiguous flush into bucket regions.
__global__ __launch_bounds__(512) void k_binfill2(
        const int* __restrict__ esrc, const int* __restrict__ edst,
        const float* __restrict__ ew, int* __restrict__ cursor,
        int2* __restrict__ bsw, int E, int B) {
    __shared__ int2 stg[CH2];            // 32 KB
    __shared__ int h[BK];                //  4 KB
    __shared__ int lcur[BK];             //  4 KB
    __shared__ int gb[BK];               //  4 KB
    __shared__ int sc[512];              //  2 KB
    const int tid = threadIdx.x;

    for (int i = tid; i < BK; i += 512) h[i] = 0;
    __syncthreads();
    int e0 = blockIdx.x * CH2;
    int e1 = min(E, e0 + CH2);
    for (int e = e0 + tid; e < e1; e += 512)
        atomicAdd(&h[edst[e] >> 7], 1);
    __syncthreads();
    // pair scan: thread t owns entries 2t, 2t+1
    int a0 = h[2 * tid], a1 = h[2 * tid + 1];
    int s  = a0 + a1;
    sc[tid] = s;
    __syncthreads();
    for (int off = 1; off < 512; off <<= 1) {
        int t = (tid >= off) ? sc[tid - off] : 0;
        __syncthreads();
        sc[tid] += t;
        __syncthreads();
    }
    int base = sc[tid] - s;               // exclusive over pairs
    lcur[2 * tid]     = base;
    lcur[2 * tid + 1] = base + a0;
    gb[2 * tid]     = a0 ? atomicAdd(&cursor[2 * tid],     a0) : 0;
    gb[2 * tid + 1] = a1 ? atomicAdd(&cursor[2 * tid + 1], a1) : 0;
    __syncthreads();
    // scatter into bucket-grouped staging; dl packed into .x bits 18..24
    for (int e = e0 + tid; e < e1; e += 512) {
        int d = edst[e];
        int b = d >> 7;
        int p = atomicAdd(&lcur[b], 1);
        stg[p] = make_int2(((d & 127) << 18) | esrc[e], __float_as_int(ew[e]));
    }
    __syncthreads();
    // contiguous flush: wave w handles buckets w, w+8, ...
    const int wid = tid >> 6, lane = tid & 63;
    for (int b = wid; b < B; b += 8) {
        int len = h[b];
        if (!len) continue;
        int lb = lcur[b] - len;
        int g  = gb[b];
        int wlen = min(len, CAPB - g);
        if (wlen <= 0) continue;
        size_t gbase = (size_t)b * CAPB + g;
        for (int i = lane; i < wlen; i += 64)
            bsw[gbase + i] = stg[lb + i];
    }
}

// counting-sort a bucket's edges in LDS; flush node-major (dl stripped).
__global__ __launch_bounds__(512) void k_csrsort(
        const int2* __restrict__ bsw, const int* __restrict__ cursor,
        int2* __restrict__ csr, int* __restrict__ off, int* __restrict__ fill,
        int N) {
    __shared__ int2 se[CAPB];            // 40 KB
    __shared__ int cur[NB];
    __shared__ int pfx[NB];
    const int b = blockIdx.x, tid = threadIdx.x;
    if (tid < NB) cur[tid] = 0;
    __syncthreads();
    const int cnt = min(cursor[b], CAPB);
    const int2* __restrict__ eb = bsw + (size_t)b * CAPB;
    for (int i = tid; i < cnt; i += 512)
        atomicAdd(&cur[eb[i].x >> 18], 1);   // pass1: counts
    __syncthreads();
    if (tid < NB) pfx[tid] = cur[tid];
    __syncthreads();
    for (int o = 1; o < NB; o <<= 1) {       // Hillis-Steele over 128
        int t = 0;
        if (tid < NB && tid >= o) t = pfx[tid - o];
        __syncthreads();
        if (tid < NB) pfx[tid] += t;
        __syncthreads();
    }
    if (tid < NB) {
        int excl = pfx[tid] - cur[tid];
        int node = b * NB + tid;
        if (node < N) { off[node] = b * CAPB + excl; fill[node] = cur[tid]; }
        cur[tid] = excl;                     // reuse as scatter cursor
    }
    __syncthreads();
    for (int i = tid; i < cnt; i += 512) {
        int2 e = eb[i];
        int p = atomicAdd(&cur[e.x >> 18], 1);
        se[p] = e;                           // pass2: LDS scatter
    }
    __syncthreads();
    int2* __restrict__ cb = csr + (size_t)b * CAPB;
    for (int i = tid; i < cnt; i += 512) {
        int2 e = se[i];
        cb[i] = make_int2(e.x & SRCMASK, e.y);   // contiguous full-line flush
    }
}

// ---------------------------------------------------------------------------
// fused agg + FC (+ optional graph pool). Wave = contiguous node chunk.
// gather: lane = (slot[2], f8[32]), float2 slices; 4-deep staging (fits regs).
// epilogue: per-lane W column in 64 VGPRs, readlane+fma, relu;
//   do_pool=0 -> store rows to outbuf; do_pool=1 -> run-length pool to hg.
// ---------------------------------------------------------------------------
__global__ __launch_bounds__(256, 4) void k_aggfc(
        const float* __restrict__ x, const int* __restrict__ off,
        const int* __restrict__ cnt_arr, const int2* __restrict__ csr,
        const float* __restrict__ W, const float* __restrict__ bvec,
        float* __restrict__ outbuf, const int* __restrict__ gid,
        float* __restrict__ hg, float* __restrict__ cntg,
        int N, int do_pool) {
    const int lane   = threadIdx.x & 63;
    const int slot   = lane >> 5;
    const int f8     = lane & 31;
    const int wave   = (blockIdx.x * blockDim.x + threadIdx.x) >> 6;
    const int nwaves = (gridDim.x * blockDim.x) >> 6;
    const float2* __restrict__ xv = (const float2*)x;

    float wc[64];
    #pragma unroll
    for (int f = 0; f < 64; ++f) wc[f] = W[f * 64 + lane];   // coalesced rows
    const float bias = bvec[lane];

    const int per   = (N + nwaves - 1) / nwaves;
    const int start = wave * per;
    const int end   = min(N, start + per);
    if (start >= N) return;

    int   curg = -1;
    float accp = 0.0f;
    int   cp   = 0;

    int cnt_p   = cnt_arr[start];
    int start_p = off[start];
    for (int node = start; node < end; ++node) {
        const int cnt = cnt_p, st = start_p;
        if (node + 1 < end) {               // contiguous header prefetch
            cnt_p   = cnt_arr[node + 1];
            start_p = off[node + 1];
        }
        int2 ee = make_int2(0, 0);          // zero-pad: w=0, s=0
        if (lane < cnt) ee = csr[st + lane];
        float2 acc0 = {0.f, 0.f}, acc1 = {0.f, 0.f};
        float  sw = 0.0f;
        for (int bk = 0; bk < cnt; bk += 64) {
            int   s_l = ee.x;
            float w_l = __int_as_float(ee.y);
            int2 en = make_int2(0, 0);
            int  rem = cnt - bk - 64;
            if (lane < rem) en = csr[st + bk + 64 + lane];
            sw += w_l;
            #pragma unroll
            for (int j = 0; j < 64; j += 8) {       // 8 edges / iter, 4 staged
                float  w[4];
                float2 v[4];
                #pragma unroll
                for (int k = 0; k < 4; ++k) {       // issue 4 gathers
                    int idx = j + 2 * k + slot;
                    int s   = __shfl(s_l, idx);
                    w[k]    = __shfl(w_l, idx);
                    v[k]    = xv[(size_t)s * 32 + f8];
                }
                acc0.x = fmaf(w[0], v[0].x, acc0.x);
                acc0.y = fmaf(w[0], v[0].y, acc0.y);
                acc1.x = fmaf(w[1], v[1].x, acc1.x);
                acc1.y = fmaf(w[1], v[1].y, acc1.y);
                acc0.x = fmaf(w[2], v[2].x, acc0.x);
                acc0.y = fmaf(w[2], v[2].y, acc0.y);
                acc1.x = fmaf(w[3], v[3].x, acc1.x);
                acc1.y = fmaf(w[3], v[3].y, acc1.y);
            }
            ee = en;
        }
        acc0.x += acc1.x; acc0.y += acc1.y;
        acc0.x += __shfl_xor(acc0.x, 32);   // both halves now hold slot-sum
        acc0.y += __shfl_xor(acc0.y, 32);
        #pragma unroll
        for (int mask = 1; mask <= 32; mask <<= 1) sw += __shfl_xor(sw, mask);
        float invw = (sw > 0.0f) ? (1.0f / sw) : 0.0f;
        float invd = 1.0f / ((float)cnt + 1.0f);
        float2 xs = xv[(size_t)node * 32 + f8];      // all lanes (dup ok)
        float2 hn;
        hn.x = (acc0.x * invw + xs.x) * invd;        // feature 2*f8
        hn.y = (acc0.y * invw + xs.y) * invd;        // feature 2*f8+1
        // FC: o[lane] = bias + sum_f hn_f * W[f][lane]; feature f lives at
        // lane (f>>1), component (f&1)
        float o0 = bias, o1 = 0.f;
        #pragma unroll
        for (int j = 0; j < 32; ++j) {
            float hx = readlane_f(hn.x, j);
            float hy = readlane_f(hn.y, j);
            o0 = fmaf(hx, wc[2 * j],     o0);
            o1 = fmaf(hy, wc[2 * j + 1], o1);
        }
        float o = fmaxf(o0 + o1, 0.0f);
        if (!do_pool) {
            outbuf[(size_t)node * 64 + lane] = o;    // coalesced 256B
        } else {
            int g = gid[node];                       // wave-uniform
            if (g != curg) {
                if (cp > 0) {
                    atomicAdd(&hg[curg * 64 + lane], accp);
                    if (lane == 0) atomicAdd(&cntg[curg], (float)cp);
                }
                curg = g; accp = 0.0f; cp = 0;
            }
            accp += o;
            ++cp;
        }
    }
    if (do_pool && cp > 0) {
        atomicAdd(&hg[curg * 64 + lane], accp);
        if (lane == 0) atomicAdd(&cntg[curg], (float)cp);
    }
}

__global__ void k_out(const float* __restrict__ hg, const float* __restrict__ cntg,
                      const float* __restrict__ Wc, const float* __restrict__ bc,
                      float* __restrict__ out, int G) {
    int t = blockIdx.x * blockDim.x + threadIdx.x;
    if (t >= G * 2) return;
    int g = t >> 1, c = t & 1;
    float ct = fmaxf(cntg[g], 1.0f);
    float o  = bc[c];
    for (int f = 0; f < 64; ++f)
        o += (hg[g * 64 + f] / ct) * Wc[f * 2 + c];
    out[t] = o;
}

// ---- fallback kernels (compact CSR) ----
__global__ void k_cnt(const int* __restrict__ edst, int* __restrict__ cnt, int E) {
    int e = blockIdx.x * blockDim.x + threadIdx.x;
    if (e < E) atomicAdd(&cnt[edst[e]], 1);
}

__global__ void k_off(const int* __restrict__ cnt, int* __restrict__ off,
                      int* __restrict__ fill, int* __restrict__ cursor, int N) {
    int i    = blockIdx.x * blockDim.x + threadIdx.x;
    int lane = threadIdx.x & 63;
    int c    = (i < N) ? cnt[i] : 0;
    int pref = c;
    #pragma unroll
    for (int d = 1; d < 64; d <<= 1) {
        int t = __shfl_up(pref, d);
        if (lane >= d) pref += t;
    }
    int total = __shfl(pref, 63);
    int base  = 0;
    if (lane == 63) base = atomicAdd(cursor, total);
    base = __shfl(base, 63);
    if (i < N) {
        int p = base + pref - c;
        off[i]  = p;
        fill[i] = p;
    }
}

__global__ void k_fill(const int* __restrict__ esrc, const int* __restrict__ edst,
                       const float* __restrict__ ew, int* __restrict__ fill,
                       int2* __restrict__ csr, int E) {
    int e = blockIdx.x * blockDim.x + threadIdx.x;
    if (e < E) {
        int d = edst[e];
        int p = atomicAdd(&fill[d], 1);
        csr[p] = make_int2(esrc[e], __float_as_int(ew[e]));
    }
}

extern "C" void kernel_launch(void* const* d_in, const int* in_sizes, int n_in,
                              void* d_out, int out_size, void* d_ws, size_t ws_size,
                              hipStream_t stream) {
    const float* in_feat = (const float*)d_in[0];
    const float* ew      = (const float*)d_in[1];
    const float* W1      = (const float*)d_in[2];
    const float* b1      = (const float*)d_in[3];
    const float* W2      = (const float*)d_in[4];
    const float* b2      = (const float*)d_in[5];
    const float* Wc      = (const float*)d_in[6];
    const float* bc      = (const float*)d_in[7];
    const int*   esrc    = (const int*)d_in[8];
    const int*   edst    = (const int*)d_in[9];
    const int*   gid     = (const int*)d_in[10];

    const int E = in_sizes[1];
    const int N = in_sizes[10];
    const int G = out_size / 2;
    float* outp = (float*)d_out;

    auto alignup = [](size_t x) { return (x + 15) & ~(size_t)15; };
    char* base = (char*)d_ws;
    const int AGG_BLK = 2048;

    // ---- main path: bucketed sort chain + fused agg (R13) ----
    const int B     = (N + NB - 1) / NB;               // 128-node buckets
    const int NBLK2 = (E + CH2 - 1) / CH2;

    size_t zhdr  = ((size_t)G * 64 + G + BK) * 4;      // hg, cntg, cursor
    size_t o_off = alignup(zhdr);
    size_t o_fil = o_off + alignup((size_t)N * 4);
    size_t o_bsw = o_fil + alignup((size_t)N * 4);
    size_t o_csr = o_bsw + alignup((size_t)B * CAPB * 8);
    size_t o_t1  = o_csr + alignup((size_t)B * CAPB * 8);
    size_t needB = o_t1 + (size_t)N * 64 * 4;

    bool cap_ok = ((size_t)E / B) + 512 < CAPB && N <= (1 << 18);

    if (ws_size >= needB && B <= BK && cap_ok) {
        float* hg     = (float*)base;
        float* cntg   = hg + (size_t)G * 64;
        int*   cursor = (int*)(cntg + G);
        int*   off    = (int*)(base + o_off);
        int*   fill   = (int*)(base + o_fil);
        int2*  bsw    = (int2*)(base + o_bsw);
        int2*  csr    = (int2*)(base + o_csr);
        float* t1     = (float*)(base + o_t1);

        hipMemsetAsync(d_ws, 0, zhdr, stream);   // hg, cntg, cursor
        k_binfill2<<<NBLK2, 512, 0, stream>>>(esrc, edst, ew, cursor, bsw, E, B);
        k_csrsort <<<B, 512, 0, stream>>>(bsw, cursor, csr, off, fill, N);
        k_aggfc<<<AGG_BLK, 256, 0, stream>>>(in_feat, off, fill, csr, W1, b1,
                                             t1, nullptr, nullptr, nullptr, N, 0);
        k_aggfc<<<AGG_BLK, 256, 0, stream>>>(t1, off, fill, csr, W2, b2,
                                             nullptr, gid, hg, cntg, N, 1);
        k_out  <<<1, 128, 0, stream>>>(hg, cntg, Wc, bc, outp, G);
        return;
    }

    // ---- fallback: 3-pass compact CSR + fused agg ----
    {
        size_t hdr = ((size_t)G * 64 + G + 1 + N) * 4;
        size_t o = 0;
        float* hg     = (float*)(base + o);
        float* cntg   = hg + (size_t)G * 64;
        int*   cursor = (int*)(cntg + G);
        int*   cnt    = cursor + 1;
        o += alignup(hdr);
        int*   off  = (int*)(base + o);  o += alignup((size_t)N * 4);
        int*   fill = (int*)(base + o);  o += alignup((size_t)N * 4);
        int2*  csr  = (int2*)(base + o); o += alignup((size_t)E * 8);
        float* t1   = (float*)(base + o);

        hipMemsetAsync(d_ws, 0, hdr, stream);
        k_cnt <<<(E + 255) / 256, 256, 0, stream>>>(edst, cnt, E);
        k_off <<<(N + 255) / 256, 256, 0, stream>>>(cnt, off, fill, cursor, N);
        k_fill<<<(E + 255) / 256, 256, 0, stream>>>(esrc, edst, ew, fill, csr, E);
        k_aggfc<<<AGG_BLK, 256, 0, stream>>>(in_feat, off, cnt, csr, W1, b1,
                                             t1, nullptr, nullptr, nullptr, N, 0);
        k_aggfc<<<AGG_BLK, 256, 0, stream>>>(t1, off, cnt, csr, W2, b2,
                                             nullptr, gid, hg, cntg, N, 1);
        k_out  <<<1, 128, 0, stream>>>(hg, cntg, Wc, bc, outp, G);
    }
}

// Round 14
// 549.998 us; speedup vs baseline: 1.8563x; 1.7066x over previous
//
#include <hip/hip_runtime.h>

// ---------------------------------------------------------------------------
// SGCN: 2-layer GraphSAGE('gcn') + EdgeWeightNorm('right') + mean-pool + FC
// N=100k nodes, E=3.2M edges, G=64 graphs, F=64 feats, fp32 throughout.
//
// R13 -> R14: R12/R13 both spilled wc[64]: compiler pinned VGPR=64 (8 waves/
// SIMD heuristic) under __launch_bounds__(256,4) and scratch-spilled the W
// column (FETCH 1.2GB). Single change: launch_bounds(256) with NO min-waves
// floor -> allocator free to take ~115 VGPRs (4 waves/SIMD = 16 waves/CU,
// same occupancy R11's split agg actually ran at). Everything else as R13.
// Pipeline: memset, binfill2, csrsort, aggfc(L1), aggfc(L2+pool), out.
// ---------------------------------------------------------------------------

#define CH2  4096   // edges per binfill2 block
#define BK   1024   // max buckets
#define NB   128    // nodes per bucket
#define CAPB 5120   // bucket capacity (mean 4096 + 16 sigma)
#define SRCMASK ((1 << 18) - 1)

__device__ __forceinline__ float readlane_f(float v, int l) {
    return __int_as_float(__builtin_amdgcn_readlane(__float_as_int(v), l));
}

// scan-free binfill: LDS hist -> pair-scan -> global span reserve ->
// LDS scatter (dl packed in .x) -> contiguous flush into bucket regions.
__global__ __launch_bounds__(512) void k_binfill2(
        const int* __restrict__ esrc, const int* __restrict__ edst,
        const float* __restrict__ ew, int* __restrict__ cursor,
        int2* __restrict__ bsw, int E, int B) {
    __shared__ int2 stg[CH2];            // 32 KB
    __shared__ int h[BK];                //  4 KB
    __shared__ int lcur[BK];             //  4 KB
    __shared__ int gb[BK];               //  4 KB
    __shared__ int sc[512];              //  2 KB
    const int tid = threadIdx.x;

    for (int i = tid; i < BK; i += 512) h[i] = 0;
    __syncthreads();
    int e0 = blockIdx.x * CH2;
    int e1 = min(E, e0 + CH2);
    for (int e = e0 + tid; e < e1; e += 512)
        atomicAdd(&h[edst[e] >> 7], 1);
    __syncthreads();
    // pair scan: thread t owns entries 2t, 2t+1
    int a0 = h[2 * tid], a1 = h[2 * tid + 1];
    int s  = a0 + a1;
    sc[tid] = s;
    __syncthreads();
    for (int off = 1; off < 512; off <<= 1) {
        int t = (tid >= off) ? sc[tid - off] : 0;
        __syncthreads();
        sc[tid] += t;
        __syncthreads();
    }
    int base = sc[tid] - s;               // exclusive over pairs
    lcur[2 * tid]     = base;
    lcur[2 * tid + 1] = base + a0;
    gb[2 * tid]     = a0 ? atomicAdd(&cursor[2 * tid],     a0) : 0;
    gb[2 * tid + 1] = a1 ? atomicAdd(&cursor[2 * tid + 1], a1) : 0;
    __syncthreads();
    // scatter into bucket-grouped staging; dl packed into .x bits 18..24
    for (int e = e0 + tid; e < e1; e += 512) {
        int d = edst[e];
        int b = d >> 7;
        int p = atomicAdd(&lcur[b], 1);
        stg[p] = make_int2(((d & 127) << 18) | esrc[e], __float_as_int(ew[e]));
    }
    __syncthreads();
    // contiguous flush: wave w handles buckets w, w+8, ...
    const int wid = tid >> 6, lane = tid & 63;
    for (int b = wid; b < B; b += 8) {
        int len = h[b];
        if (!len) continue;
        int lb = lcur[b] - len;
        int g  = gb[b];
        int wlen = min(len, CAPB - g);
        if (wlen <= 0) continue;
        size_t gbase = (size_t)b * CAPB + g;
        for (int i = lane; i < wlen; i += 64)
            bsw[gbase + i] = stg[lb + i];
    }
}

// counting-sort a bucket's edges in LDS; flush node-major (dl stripped).
__global__ __launch_bounds__(512) void k_csrsort(
        const int2* __restrict__ bsw, const int* __restrict__ cursor,
        int2* __restrict__ csr, int* __restrict__ off, int* __restrict__ fill,
        int N) {
    __shared__ int2 se[CAPB];            // 40 KB
    __shared__ int cur[NB];
    __shared__ int pfx[NB];
    const int b = blockIdx.x, tid = threadIdx.x;
    if (tid < NB) cur[tid] = 0;
    __syncthreads();
    const int cnt = min(cursor[b], CAPB);
    const int2* __restrict__ eb = bsw + (size_t)b * CAPB;
    for (int i = tid; i < cnt; i += 512)
        atomicAdd(&cur[eb[i].x >> 18], 1);   // pass1: counts
    __syncthreads();
    if (tid < NB) pfx[tid] = cur[tid];
    __syncthreads();
    for (int o = 1; o < NB; o <<= 1) {       // Hillis-Steele over 128
        int t = 0;
        if (tid < NB && tid >= o) t = pfx[tid - o];
        __syncthreads();
        if (tid < NB) pfx[tid] += t;
        __syncthreads();
    }
    if (tid < NB) {
        int excl = pfx[tid] - cur[tid];
        int node = b * NB + tid;
        if (node < N) { off[node] = b * CAPB + excl; fill[node] = cur[tid]; }
        cur[tid] = excl;                     // reuse as scatter cursor
    }
    __syncthreads();
    for (int i = tid; i < cnt; i += 512) {
        int2 e = eb[i];
        int p = atomicAdd(&cur[e.x >> 18], 1);
        se[p] = e;                           // pass2: LDS scatter
    }
    __syncthreads();
    int2* __restrict__ cb = csr + (size_t)b * CAPB;
    for (int i = tid; i < cnt; i += 512) {
        int2 e = se[i];
        cb[i] = make_int2(e.x & SRCMASK, e.y);   // contiguous full-line flush
    }
}

// ---------------------------------------------------------------------------
// fused agg + FC (+ optional graph pool). Wave = contiguous node chunk.
// gather: lane = (slot[2], f8[32]), float2 slices; 4-deep staging.
// epilogue: per-lane W column in 64 VGPRs, readlane+fma, relu;
//   do_pool=0 -> store rows to outbuf; do_pool=1 -> run-length pool to hg.
// NOTE: launch_bounds(256) with NO min-waves arg -- a (256,4) floor made the
// allocator pin 64 VGPRs and scratch-spill wc[64] (R12/R13: FETCH 1.2GB).
// ---------------------------------------------------------------------------
__global__ __launch_bounds__(256) void k_aggfc(
        const float* __restrict__ x, const int* __restrict__ off,
        const int* __restrict__ cnt_arr, const int2* __restrict__ csr,
        const float* __restrict__ W, const float* __restrict__ bvec,
        float* __restrict__ outbuf, const int* __restrict__ gid,
        float* __restrict__ hg, float* __restrict__ cntg,
        int N, int do_pool) {
    const int lane   = threadIdx.x & 63;
    const int slot   = lane >> 5;
    const int f8     = lane & 31;
    const int wave   = (blockIdx.x * blockDim.x + threadIdx.x) >> 6;
    const int nwaves = (gridDim.x * blockDim.x) >> 6;
    const float2* __restrict__ xv = (const float2*)x;

    float wc[64];
    #pragma unroll
    for (int f = 0; f < 64; ++f) wc[f] = W[f * 64 + lane];   // coalesced rows
    const float bias = bvec[lane];

    const int per   = (N + nwaves - 1) / nwaves;
    const int start = wave * per;
    const int end   = min(N, start + per);
    if (start >= N) return;

    int   curg = -1;
    float accp = 0.0f;
    int   cp   = 0;

    int cnt_p   = cnt_arr[start];
    int start_p = off[start];
    for (int node = start; node < end; ++node) {
        const int cnt = cnt_p, st = start_p;
        if (node + 1 < end) {               // contiguous header prefetch
            cnt_p   = cnt_arr[node + 1];
            start_p = off[node + 1];
        }
        int2 ee = make_int2(0, 0);          // zero-pad: w=0, s=0
        if (lane < cnt) ee = csr[st + lane];
        float2 acc0 = {0.f, 0.f}, acc1 = {0.f, 0.f};
        float  sw = 0.0f;
        for (int bk = 0; bk < cnt; bk += 64) {
            int   s_l = ee.x;
            float w_l = __int_as_float(ee.y);
            int2 en = make_int2(0, 0);
            int  rem = cnt - bk - 64;
            if (lane < rem) en = csr[st + bk + 64 + lane];
            sw += w_l;
            #pragma unroll
            for (int j = 0; j < 64; j += 8) {       // 8 edges / iter, 4 staged
                float  w[4];
                float2 v[4];
                #pragma unroll
                for (int k = 0; k < 4; ++k) {       // issue 4 gathers
                    int idx = j + 2 * k + slot;
                    int s   = __shfl(s_l, idx);
                    w[k]    = __shfl(w_l, idx);
                    v[k]    = xv[(size_t)s * 32 + f8];
                }
                acc0.x = fmaf(w[0], v[0].x, acc0.x);
                acc0.y = fmaf(w[0], v[0].y, acc0.y);
                acc1.x = fmaf(w[1], v[1].x, acc1.x);
                acc1.y = fmaf(w[1], v[1].y, acc1.y);
                acc0.x = fmaf(w[2], v[2].x, acc0.x);
                acc0.y = fmaf(w[2], v[2].y, acc0.y);
                acc1.x = fmaf(w[3], v[3].x, acc1.x);
                acc1.y = fmaf(w[3], v[3].y, acc1.y);
            }
            ee = en;
        }
        acc0.x += acc1.x; acc0.y += acc1.y;
        acc0.x += __shfl_xor(acc0.x, 32);   // both halves now hold slot-sum
        acc0.y += __shfl_xor(acc0.y, 32);
        #pragma unroll
        for (int mask = 1; mask <= 32; mask <<= 1) sw += __shfl_xor(sw, mask);
        float invw = (sw > 0.0f) ? (1.0f / sw) : 0.0f;
        float invd = 1.0f / ((float)cnt + 1.0f);
        float2 xs = xv[(size_t)node * 32 + f8];      // all lanes (dup ok)
        float2 hn;
        hn.x = (acc0.x * invw + xs.x) * invd;        // feature 2*f8
        hn.y = (acc0.y * invw + xs.y) * invd;        // feature 2*f8+1
        // FC: o[lane] = bias + sum_f hn_f * W[f][lane]; feature f lives at
        // lane (f>>1), component (f&1)
        float o0 = bias, o1 = 0.f;
        #pragma unroll
        for (int j = 0; j < 32; ++j) {
            float hx = readlane_f(hn.x, j);
            float hy = readlane_f(hn.y, j);
            o0 = fmaf(hx, wc[2 * j],     o0);
            o1 = fmaf(hy, wc[2 * j + 1], o1);
        }
        float o = fmaxf(o0 + o1, 0.0f);
        if (!do_pool) {
            outbuf[(size_t)node * 64 + lane] = o;    // coalesced 256B
        } else {
            int g = gid[node];                       // wave-uniform
            if (g != curg) {
                if (cp > 0) {
                    atomicAdd(&hg[curg * 64 + lane], accp);
                    if (lane == 0) atomicAdd(&cntg[curg], (float)cp);
                }
                curg = g; accp = 0.0f; cp = 0;
            }
            accp += o;
            ++cp;
        }
    }
    if (do_pool && cp > 0) {
        atomicAdd(&hg[curg * 64 + lane], accp);
        if (lane == 0) atomicAdd(&cntg[curg], (float)cp);
    }
}

__global__ void k_out(const float* __restrict__ hg, const float* __restrict__ cntg,
                      const float* __restrict__ Wc, const float* __restrict__ bc,
                      float* __restrict__ out, int G) {
    int t = blockIdx.x * blockDim.x + threadIdx.x;
    if (t >= G * 2) return;
    int g = t >> 1, c = t & 1;
    float ct = fmaxf(cntg[g], 1.0f);
    float o  = bc[c];
    for (int f = 0; f < 64; ++f)
        o += (hg[g * 64 + f] / ct) * Wc[f * 2 + c];
    out[t] = o;
}

// ---- fallback kernels (compact CSR) ----
__global__ void k_cnt(const int* __restrict__ edst, int* __restrict__ cnt, int E) {
    int e = blockIdx.x * blockDim.x + threadIdx.x;
    if (e < E) atomicAdd(&cnt[edst[e]], 1);
}

__global__ void k_off(const int* __restrict__ cnt, int* __restrict__ off,
                      int* __restrict__ fill, int* __restrict__ cursor, int N) {
    int i    = blockIdx.x * blockDim.x + threadIdx.x;
    int lane = threadIdx.x & 63;
    int c    = (i < N) ? cnt[i] : 0;
    int pref = c;
    #pragma unroll
    for (int d = 1; d < 64; d <<= 1) {
        int t = __shfl_up(pref, d);
        if (lane >= d) pref += t;
    }
    int total = __shfl(pref, 63);
    int base  = 0;
    if (lane == 63) base = atomicAdd(cursor, total);
    base = __shfl(base, 63);
    if (i < N) {
        int p = base + pref - c;
        off[i]  = p;
        fill[i] = p;
    }
}

__global__ void k_fill(const int* __restrict__ esrc, const int* __restrict__ edst,
                       const float* __restrict__ ew, int* __restrict__ fill,
                       int2* __restrict__ csr, int E) {
    int e = blockIdx.x * blockDim.x + threadIdx.x;
    if (e < E) {
        int d = edst[e];
        int p = atomicAdd(&fill[d], 1);
        csr[p] = make_int2(esrc[e], __float_as_int(ew[e]));
    }
}

extern "C" void kernel_launch(void* const* d_in, const int* in_sizes, int n_in,
                              void* d_out, int out_size, void* d_ws, size_t ws_size,
                              hipStream_t stream) {
    const float* in_feat = (const float*)d_in[0];
    const float* ew      = (const float*)d_in[1];
    const float* W1      = (const float*)d_in[2];
    const float* b1      = (const float*)d_in[3];
    const float* W2      = (const float*)d_in[4];
    const float* b2      = (const float*)d_in[5];
    const float* Wc      = (const float*)d_in[6];
    const float* bc      = (const float*)d_in[7];
    const int*   esrc    = (const int*)d_in[8];
    const int*   edst    = (const int*)d_in[9];
    const int*   gid     = (const int*)d_in[10];

    const int E = in_sizes[1];
    const int N = in_sizes[10];
    const int G = out_size / 2;
    float* outp = (float*)d_out;

    auto alignup = [](size_t x) { return (x + 15) & ~(size_t)15; };
    char* base = (char*)d_ws;
    const int AGG_BLK = 2048;

    // ---- main path: bucketed sort chain + fused agg (R14) ----
    const int B     = (N + NB - 1) / NB;               // 128-node buckets
    const int NBLK2 = (E + CH2 - 1) / CH2;

    size_t zhdr  = ((size_t)G * 64 + G + BK) * 4;      // hg, cntg, cursor
    size_t o_off = alignup(zhdr);
    size_t o_fil = o_off + alignup((size_t)N * 4);
    size_t o_bsw = o_fil + alignup((size_t)N * 4);
    size_t o_csr = o_bsw + alignup((size_t)B * CAPB * 8);
    size_t o_t1  = o_csr + alignup((size_t)B * CAPB * 8);
    size_t needB = o_t1 + (size_t)N * 64 * 4;

    bool cap_ok = ((size_t)E / B) + 512 < CAPB && N <= (1 << 18);

    if (ws_size >= needB && B <= BK && cap_ok) {
        float* hg     = (float*)base;
        float* cntg   = hg + (size_t)G * 64;
        int*   cursor = (int*)(cntg + G);
        int*   off    = (int*)(base + o_off);
        int*   fill   = (int*)(base + o_fil);
        int2*  bsw    = (int2*)(base + o_bsw);
        int2*  csr    = (int2*)(base + o_csr);
        float* t1     = (float*)(base + o_t1);

        hipMemsetAsync(d_ws, 0, zhdr, stream);   // hg, cntg, cursor
        k_binfill2<<<NBLK2, 512, 0, stream>>>(esrc, edst, ew, cursor, bsw, E, B);
        k_csrsort <<<B, 512, 0, stream>>>(bsw, cursor, csr, off, fill, N);
        k_aggfc<<<AGG_BLK, 256, 0, stream>>>(in_feat, off, fill, csr, W1, b1,
                                             t1, nullptr, nullptr, nullptr, N, 0);
        k_aggfc<<<AGG_BLK, 256, 0, stream>>>(t1, off, fill, csr, W2, b2,
                                             nullptr, gid, hg, cntg, N, 1);
        k_out  <<<1, 128, 0, stream>>>(hg, cntg, Wc, bc, outp, G);
        return;
    }

    // ---- fallback: 3-pass compact CSR + fused agg ----
    {
        size_t hdr = ((size_t)G * 64 + G + 1 + N) * 4;
        size_t o = 0;
        float* hg     = (float*)(base + o);
        float* cntg   = hg + (size_t)G * 64;
        int*   cursor = (int*)(cntg + G);
        int*   cnt    = cursor + 1;
        o += alignup(hdr);
        int*   off  = (int*)(base + o);  o += alignup((size_t)N * 4);
        int*   fill = (int*)(base + o);  o += alignup((size_t)N * 4);
        int2*  csr  = (int2*)(base + o); o += alignup((size_t)E * 8);
        float* t1   = (float*)(base + o);

        hipMemsetAsync(d_ws, 0, hdr, stream);
        k_cnt <<<(E + 255) / 256, 256, 0, stream>>>(edst, cnt, E);
        k_off <<<(N + 255) / 256, 256, 0, stream>>>(cnt, off, fill, cursor, N);
        k_fill<<<(E + 255) / 256, 256, 0, stream>>>(esrc, edst, ew, fill, csr, E);
        k_aggfc<<<AGG_BLK, 256, 0, stream>>>(in_feat, off, cnt, csr, W1, b1,
                                             t1, nullptr, nullptr, nullptr, N, 0);
        k_aggfc<<<AGG_BLK, 256, 0, stream>>>(t1, off, cnt, csr, W2, b2,
                                             nullptr, gid, hg, cntg, N, 1);
        k_out  <<<1, 128, 0, stream>>>(hg, cntg, Wc, bc, outp, G);
    }
}